// Round 3
// baseline (396.720 us; speedup 1.0000x reference)
//
#include <hip/hip_runtime.h>

#define NUM_CLASSES 80
#define MAX_O 16

// ---------------- device helpers ----------------

// balanced_l1: R_ALPHA=0.5, R_GAMMA=1.5, R_BETA=0.11, b = e^3 - 1
__device__ __forceinline__ float bl1f(float diff) {
  const float bc = 19.085537f;  // float32(e^3 - 1)
  float d = fabsf(diff);
  if (d < 0.11f) {
    return 0.5f / bc * (bc * d + 1.0f) * __logf(1.0f + bc * d / 0.11f) - 0.5f * d;
  }
  return 1.5f * d + 1.5f / bc - 0.5f * 0.11f;
}

// focal: F_ALPHA=0.25, F_GAMMA=1.0 (pt**gamma == pt).
// Fast form: 1 v_exp + 1 v_log + 1 v_rcp + ~10 fma.
__device__ __forceinline__ float focal1(float l, float t) {
  float a = fabsf(l);
  float q = __expf(-a);                        // exp(-|l|)
  float lp = __logf(1.0f + q);                 // log1p(exp(-|l|))
  float bce = fmaxf(l, 0.0f) - l * t + lp;
  float r = __builtin_amdgcn_rcpf(1.0f + q);
  float p = (l >= 0.0f) ? r : q * r;           // sigmoid(l)
  float pt = t + p * (1.0f - 2.0f * t);        // (1-p)t + p(1-t)
  float w = (0.75f - 0.5f * t) * pt;           // (a*t+(1-a)(1-t)) * pt
  return bce * w;
}

// ---------------- kernel 0: zero accumulators + argmax keys ----------------

__global__ void init_kernel(double* __restrict__ acc,
                            unsigned long long* __restrict__ gkey, int nkey) {
  int i = blockIdx.x * blockDim.x + threadIdx.x;
  if (i < nkey) gkey[i] = 0ull;
  if (i == 0) { acc[0] = 0.0; acc[1] = 0.0; acc[2] = 0.0; }
}

// ---------------- kernel 1a: matching, parallel over priors ----------------
// grid = (Nb, B). Each thread: per-prior max/argmax over truths (writes
// bto/bti), plus per-truth best-prior candidate, wave-shuffle-reduced and
// atomicMax'd into gkey[b*O+t]. Key packs (bits(ov)<<32)|(~p) so ties pick
// the smallest prior index (jnp.argmax semantics).

__global__ void match_partial_kernel(const float* __restrict__ priors,
                                     const float* __restrict__ targets,
                                     float* __restrict__ bto,
                                     int* __restrict__ bti,
                                     unsigned long long* __restrict__ gkey,
                                     int P, int O) {
  int b = blockIdx.y;
  int tid = threadIdx.x;

  __shared__ float s_t[MAX_O][4];
  __shared__ float s_area[MAX_O];
  if (tid < O) {
    const float* t = targets + ((size_t)b * O + tid) * 5;
    float x1 = t[0], y1 = t[1], x2 = t[2], y2 = t[3];
    s_t[tid][0] = x1; s_t[tid][1] = y1; s_t[tid][2] = x2; s_t[tid][3] = y2;
    s_area[tid] = (x2 - x1) * (y2 - y1);
  }
  __syncthreads();

  float bov[MAX_O];
  unsigned bpi[MAX_O];
#pragma unroll
  for (int t = 0; t < MAX_O; ++t) { bov[t] = -1.0f; bpi[t] = 0u; }

  for (int p = blockIdx.x * blockDim.x + tid; p < P;
       p += gridDim.x * blockDim.x) {
    const float* pr = priors + (size_t)p * 4;
    float cx = pr[0], cy = pr[1], w = pr[2], h = pr[3];
    float px1 = cx - 0.5f * w, py1 = cy - 0.5f * h;
    float px2 = cx + 0.5f * w, py2 = cy + 0.5f * h;
    float parea = (px2 - px1) * (py2 - py1);

    float best = -1.0f;
    int bestt = 0;
#pragma unroll
    for (int t = 0; t < MAX_O; ++t) {
      if (t < O) {
        float lx = fmaxf(s_t[t][0], px1);
        float ly = fmaxf(s_t[t][1], py1);
        float rx = fminf(s_t[t][2], px2);
        float ry = fminf(s_t[t][3], py2);
        float iw = fmaxf(rx - lx, 0.0f);
        float ih = fmaxf(ry - ly, 0.0f);
        float inter = iw * ih;
        float ov = inter / (s_area[t] + parea - inter);
        if (ov > best) { best = ov; bestt = t; }             // first-max axis=0
        if (ov > bov[t]) { bov[t] = ov; bpi[t] = (unsigned)p; }
      }
    }
    bto[(size_t)b * P + p] = best;
    bti[(size_t)b * P + p] = bestt;
  }

  // wave-level reduce per truth, then one global atomicMax per wave
  int lane = tid & 63;
#pragma unroll
  for (int t = 0; t < MAX_O; ++t) {
    if (t < O) {
      unsigned long long key = (bov[t] >= 0.0f)
          ? (((unsigned long long)__float_as_uint(bov[t]) << 32) |
             (unsigned long long)(0xFFFFFFFFu - bpi[t]))
          : 0ull;
      for (int o = 32; o > 0; o >>= 1) {
        unsigned long long other = __shfl_xor(key, o, 64);
        if (other > key) key = other;
      }
      if (lane == 0 && key != 0ull)
        atomicMax(&gkey[(size_t)b * O + t], key);
    }
  }
}

// ---------------- kernel 1b: override ----------------
// Sequential t=0..O-1 per batch (last-wins for duplicate best priors).

__global__ void match_override_kernel(const unsigned long long* __restrict__ gkey,
                                      float* __restrict__ bto,
                                      int* __restrict__ bti,
                                      int P, int O) {
  int b = blockIdx.x;
  if (threadIdx.x == 0) {
    for (int t = 0; t < O; ++t) {
      unsigned p = 0xFFFFFFFFu - (unsigned)(gkey[(size_t)b * O + t] & 0xFFFFFFFFull);
      bto[(size_t)b * P + p] = 2.0f;
      bti[(size_t)b * P + p] = t;
    }
  }
}

// ---------------- kernel 2: fused conf (focal) + loc loss ----------------
// Grid-stride over B*P*CH float4 chunks (CH=20 per 80-class row): perfectly
// coalesced 16B loads of the 168 MB conf tensor. The chunk==0 thread of each
// row additionally computes the balanced-L1 loc loss and the pos count.

__global__ void fused_loss_kernel(const float* __restrict__ conf,
                                  const float* __restrict__ loc_data,
                                  const float* __restrict__ priors,
                                  const float* __restrict__ targets,
                                  const float* __restrict__ bto,
                                  const int* __restrict__ bti,
                                  double* __restrict__ acc,
                                  int B, int P, int O) {
  __shared__ double sbuf_c[4];
  __shared__ double sbuf_l[4];
  __shared__ double sbuf_n[4];
  const int CH = NUM_CLASSES / 4;  // 20
  int total = B * P * CH;
  float csum = 0.0f;   // conf loss
  float lsum = 0.0f;   // loc loss
  float nsum = 0.0f;   // pos count
  for (int idx = blockIdx.x * blockDim.x + threadIdx.x; idx < total;
       idx += gridDim.x * blockDim.x) {
    int row = idx / CH;
    int chunk = idx - row * CH;
    float ov = bto[row];
    bool pos = ov >= 0.5f;
    bool neg = ov < 0.4f;

    int b = row / P;
    int p = row - b * P;
    int t = bti[row];
    const float* tr = targets + ((size_t)b * O + t) * 5;

    if (pos || neg) {
      int cls = 0;  // conf_eff = 0 when not pos
      if (pos) cls = (int)tr[4] + 1;
      float4 l4 = ((const float4*)(conf + (size_t)row * NUM_CLASSES))[chunk];
      int c0 = chunk * 4 + 1;  // classes are 1..80
      csum += focal1(l4.x, cls == c0     ? 1.0f : 0.0f);
      csum += focal1(l4.y, cls == c0 + 1 ? 1.0f : 0.0f);
      csum += focal1(l4.z, cls == c0 + 2 ? 1.0f : 0.0f);
      csum += focal1(l4.w, cls == c0 + 3 ? 1.0f : 0.0f);
    }

    if (pos && chunk == 0) {
      nsum += 1.0f;
      float x1 = tr[0], y1 = tr[1], x2 = tr[2], y2 = tr[3];
      const float* pr = priors + (size_t)p * 4;
      float cx = pr[0], cy = pr[1], w = pr[2], h = pr[3];
      float gcx = ((x1 + x2) * 0.5f - cx) / (0.1f * w);
      float gcy = ((y1 + y2) * 0.5f - cy) / (0.1f * h);
      float gw = __logf((x2 - x1) / w) * 5.0f;   // /0.2
      float gh = __logf((y2 - y1) / h) * 5.0f;
      const float* ld = loc_data + (size_t)row * 4;
      lsum += bl1f(ld[0] - gcx) + bl1f(ld[1] - gcy) +
              bl1f(ld[2] - gw) + bl1f(ld[3] - gh);
    }
  }
  for (int o = 32; o > 0; o >>= 1) {
    csum += __shfl_down(csum, o, 64);
    lsum += __shfl_down(lsum, o, 64);
    nsum += __shfl_down(nsum, o, 64);
  }
  int lane = threadIdx.x & 63, wid = threadIdx.x >> 6;
  if (lane == 0) {
    sbuf_c[wid] = (double)csum;
    sbuf_l[wid] = (double)lsum;
    sbuf_n[wid] = (double)nsum;
  }
  __syncthreads();
  if (threadIdx.x == 0) {
    atomicAdd(&acc[1], sbuf_c[0] + sbuf_c[1] + sbuf_c[2] + sbuf_c[3]);
    atomicAdd(&acc[0], sbuf_l[0] + sbuf_l[1] + sbuf_l[2] + sbuf_l[3]);
    atomicAdd(&acc[2], sbuf_n[0] + sbuf_n[1] + sbuf_n[2] + sbuf_n[3]);
  }
}

// ---------------- kernel 3: finalize ----------------

__global__ void final_kernel(const double* __restrict__ acc,
                             float* __restrict__ out) {
  if (threadIdx.x == 0) {
    double pn = acc[2] > 1.0 ? acc[2] : 1.0;
    out[0] = (float)(acc[0] / (pn * 4.0));
    out[1] = (float)(acc[1] / pn);
  }
}

// ---------------- launch ----------------

extern "C" void kernel_launch(void* const* d_in, const int* in_sizes, int n_in,
                              void* d_out, int out_size, void* d_ws, size_t ws_size,
                              hipStream_t stream) {
  const float* loc_data  = (const float*)d_in[0];
  const float* conf_data = (const float*)d_in[1];
  const float* priors    = (const float*)d_in[2];
  const float* targets   = (const float*)d_in[3];
  float* out = (float*)d_out;

  int P  = in_sizes[2] / 4;        // 16384
  int BP = in_sizes[0] / 4;        // B*P
  int B  = BP / P;                 // 32
  int O  = in_sizes[3] / (B * 5);  // 16

  // workspace layout: bto (BP f32) | bti (BP i32) | gkey (B*O u64) | acc (3 f64)
  float* bto  = (float*)d_ws;
  int* bti    = (int*)((char*)d_ws + (size_t)BP * 4);
  unsigned long long* gkey = (unsigned long long*)((char*)d_ws + (size_t)BP * 8);
  double* acc = (double*)((char*)d_ws + (size_t)BP * 8 + (size_t)B * O * 8);

  int nkey = B * O;
  hipLaunchKernelGGL(init_kernel, dim3(1), dim3(1024), 0, stream, acc, gkey, nkey);

  int nbx = (P + 255) / 256;  // 64 slices of 256 priors
  hipLaunchKernelGGL(match_partial_kernel, dim3(nbx, B), dim3(256), 0, stream,
                     priors, targets, bto, bti, gkey, P, O);
  hipLaunchKernelGGL(match_override_kernel, dim3(B), dim3(64), 0, stream,
                     gkey, bto, bti, P, O);
  hipLaunchKernelGGL(fused_loss_kernel, dim3(2048), dim3(256), 0, stream,
                     conf_data, loc_data, priors, targets, bto, bti, acc, B, P, O);
  hipLaunchKernelGGL(final_kernel, dim3(1), dim3(64), 0, stream, acc, out);
}

// Round 4
// 352.383 us; speedup vs baseline: 1.1258x; 1.1258x over previous
//
#include <hip/hip_runtime.h>

#define NUM_CLASSES 80
#define MAX_O 16

// ---------------- device helpers ----------------

// balanced_l1: R_ALPHA=0.5, R_GAMMA=1.5, R_BETA=0.11, b = e^3 - 1
__device__ __forceinline__ float bl1f(float diff) {
  const float bc = 19.085537f;  // float32(e^3 - 1)
  float d = fabsf(diff);
  if (d < 0.11f) {
    return 0.5f / bc * (bc * d + 1.0f) * __logf(1.0f + bc * d / 0.11f) - 0.5f * d;
  }
  return 1.5f * d + 1.5f / bc - 0.5f * 0.11f;
}

// focal with t=0: (max(l,0)+log1p(exp(-|l|))) * 0.75 * sigmoid(l)
__device__ __forceinline__ float focal0(float l) {
  float a = fabsf(l);
  float q = __expf(-a);
  float lp = __logf(1.0f + q);
  float r = __builtin_amdgcn_rcpf(1.0f + q);
  float p = (l >= 0.0f) ? r : q * r;
  return (fmaxf(l, 0.0f) + lp) * (0.75f * p);
}

// focal(l, t=1) - focal(l, t=0): correction for the single positive class
__device__ __forceinline__ float focal_delta(float l) {
  float a = fabsf(l);
  float q = __expf(-a);
  float lp = __logf(1.0f + q);
  float r = __builtin_amdgcn_rcpf(1.0f + q);
  float p = (l >= 0.0f) ? r : q * r;
  float f1 = (fmaxf(l, 0.0f) - l + lp) * (0.25f * (1.0f - p));
  float f0 = (fmaxf(l, 0.0f) + lp) * (0.75f * p);
  return f1 - f0;
}

// ---------------- kernel 0: zero accumulators + argmax keys ----------------

__global__ void init_kernel(double* __restrict__ acc,
                            unsigned long long* __restrict__ gkey, int nkey) {
  int i = blockIdx.x * blockDim.x + threadIdx.x;
  if (i < nkey) gkey[i] = 0ull;
  if (i == 0) { acc[0] = 0.0; acc[1] = 0.0; acc[2] = 0.0; }
}

// ---------------- kernel 1a: matching, parallel over priors ----------------

__global__ void match_partial_kernel(const float* __restrict__ priors,
                                     const float* __restrict__ targets,
                                     float* __restrict__ bto,
                                     int* __restrict__ bti,
                                     unsigned long long* __restrict__ gkey,
                                     int P, int O) {
  int b = blockIdx.y;
  int tid = threadIdx.x;

  __shared__ float s_t[MAX_O][4];
  __shared__ float s_area[MAX_O];
  if (tid < O) {
    const float* t = targets + ((size_t)b * O + tid) * 5;
    float x1 = t[0], y1 = t[1], x2 = t[2], y2 = t[3];
    s_t[tid][0] = x1; s_t[tid][1] = y1; s_t[tid][2] = x2; s_t[tid][3] = y2;
    s_area[tid] = (x2 - x1) * (y2 - y1);
  }
  __syncthreads();

  float bov[MAX_O];
  unsigned bpi[MAX_O];
#pragma unroll
  for (int t = 0; t < MAX_O; ++t) { bov[t] = -1.0f; bpi[t] = 0u; }

  for (int p = blockIdx.x * blockDim.x + tid; p < P;
       p += gridDim.x * blockDim.x) {
    const float* pr = priors + (size_t)p * 4;
    float cx = pr[0], cy = pr[1], w = pr[2], h = pr[3];
    float px1 = cx - 0.5f * w, py1 = cy - 0.5f * h;
    float px2 = cx + 0.5f * w, py2 = cy + 0.5f * h;
    float parea = (px2 - px1) * (py2 - py1);

    float best = -1.0f;
    int bestt = 0;
#pragma unroll
    for (int t = 0; t < MAX_O; ++t) {
      if (t < O) {
        float lx = fmaxf(s_t[t][0], px1);
        float ly = fmaxf(s_t[t][1], py1);
        float rx = fminf(s_t[t][2], px2);
        float ry = fminf(s_t[t][3], py2);
        float iw = fmaxf(rx - lx, 0.0f);
        float ih = fmaxf(ry - ly, 0.0f);
        float inter = iw * ih;
        float ov = inter / (s_area[t] + parea - inter);
        if (ov > best) { best = ov; bestt = t; }             // first-max axis=0
        if (ov > bov[t]) { bov[t] = ov; bpi[t] = (unsigned)p; }
      }
    }
    bto[(size_t)b * P + p] = best;
    bti[(size_t)b * P + p] = bestt;
  }

  int lane = tid & 63;
#pragma unroll
  for (int t = 0; t < MAX_O; ++t) {
    if (t < O) {
      unsigned long long key = (bov[t] >= 0.0f)
          ? (((unsigned long long)__float_as_uint(bov[t]) << 32) |
             (unsigned long long)(0xFFFFFFFFu - bpi[t]))
          : 0ull;
      for (int o = 32; o > 0; o >>= 1) {
        unsigned long long other = __shfl_xor(key, o, 64);
        if (other > key) key = other;
      }
      if (lane == 0 && key != 0ull)
        atomicMax(&gkey[(size_t)b * O + t], key);
    }
  }
}

// ---------------- kernel 1b: override ----------------

__global__ void match_override_kernel(const unsigned long long* __restrict__ gkey,
                                      float* __restrict__ bto,
                                      int* __restrict__ bti,
                                      int P, int O) {
  int b = blockIdx.x;
  if (threadIdx.x == 0) {
    for (int t = 0; t < O; ++t) {
      unsigned p = 0xFFFFFFFFu - (unsigned)(gkey[(size_t)b * O + t] & 0xFFFFFFFFull);
      bto[(size_t)b * P + p] = 2.0f;
      bti[(size_t)b * P + p] = t;
    }
  }
}

// ---------------- kernel 2: loc loss + pos count + row descriptor ----------
// Grid-stride over B*P rows. Writes rowcls[row]: -1 = skip (0.4<=ov<0.5),
// 0 = negative (all-zero one-hot), 1..80 = positive class. This removes the
// bti/targets indirection from the conf kernel's hot loop.

__global__ void loc_rowcls_kernel(const float* __restrict__ loc_data,
                                  const float* __restrict__ priors,
                                  const float* __restrict__ targets,
                                  const float* __restrict__ bto,
                                  const int* __restrict__ bti,
                                  int* __restrict__ rowcls,
                                  double* __restrict__ acc,
                                  int B, int P, int O) {
  __shared__ double sbuf_l[4];
  __shared__ double sbuf_n[4];
  int n = B * P;
  float lsum = 0.0f;
  float nsum = 0.0f;
  for (int idx = blockIdx.x * blockDim.x + threadIdx.x; idx < n;
       idx += gridDim.x * blockDim.x) {
    float ov = bto[idx];
    int cls;
    if (ov >= 0.5f) {
      nsum += 1.0f;
      int b = idx / P;
      int p = idx - b * P;
      int t = bti[idx];
      const float* tr = targets + ((size_t)b * O + t) * 5;
      float x1 = tr[0], y1 = tr[1], x2 = tr[2], y2 = tr[3];
      cls = (int)tr[4] + 1;
      const float* pr = priors + (size_t)p * 4;
      float cx = pr[0], cy = pr[1], w = pr[2], h = pr[3];
      float gcx = ((x1 + x2) * 0.5f - cx) / (0.1f * w);
      float gcy = ((y1 + y2) * 0.5f - cy) / (0.1f * h);
      float gw = __logf((x2 - x1) / w) * 5.0f;   // /0.2
      float gh = __logf((y2 - y1) / h) * 5.0f;
      const float* ld = loc_data + (size_t)idx * 4;
      lsum += bl1f(ld[0] - gcx) + bl1f(ld[1] - gcy) +
              bl1f(ld[2] - gw) + bl1f(ld[3] - gh);
    } else {
      cls = (ov < 0.4f) ? 0 : -1;
    }
    rowcls[idx] = cls;
  }
  for (int o = 32; o > 0; o >>= 1) {
    lsum += __shfl_down(lsum, o, 64);
    nsum += __shfl_down(nsum, o, 64);
  }
  int lane = threadIdx.x & 63, wid = threadIdx.x >> 6;
  if (lane == 0) { sbuf_l[wid] = (double)lsum; sbuf_n[wid] = (double)nsum; }
  __syncthreads();
  if (threadIdx.x == 0) {
    atomicAdd(&acc[0], sbuf_l[0] + sbuf_l[1] + sbuf_l[2] + sbuf_l[3]);
    atomicAdd(&acc[2], sbuf_n[0] + sbuf_n[1] + sbuf_n[2] + sbuf_n[3]);
  }
}

// ---------------- kernel 3: conf (focal) loss ----------------
// Grid-stride over B*P*10 8-element chunks. The rowcls load and the two
// float4 conf loads are all independent (no load->branch->load chain).
// All elements computed as t=0; the single positive class gets a rare
// focal_delta correction.

__global__ void conf_loss_kernel(const float4* __restrict__ conf4,
                                 const int* __restrict__ rowcls,
                                 double* __restrict__ acc,
                                 int total) {
  __shared__ double sbuf[4];
  float sum = 0.0f;
  for (int idx = blockIdx.x * blockDim.x + threadIdx.x; idx < total;
       idx += gridDim.x * blockDim.x) {
    int row = idx / 10;          // magic-mul division
    int c = idx - row * 10;      // 8-elem chunk within row
    int cls = rowcls[row];       // independent of conf loads
    const float4* base = conf4 + (size_t)row * 20 + (size_t)c * 2;
    float4 u = base[0];
    float4 v = base[1];
    float s = focal0(u.x) + focal0(u.y) + focal0(u.z) + focal0(u.w) +
              focal0(v.x) + focal0(v.y) + focal0(v.z) + focal0(v.w);
    if (cls > 0) {
      int j = cls - 1 - c * 8;   // position of the positive class in chunk
      if ((unsigned)j < 8u) {
        float l = (j < 4) ? (j == 0 ? u.x : j == 1 ? u.y : j == 2 ? u.z : u.w)
                          : (j == 4 ? v.x : j == 5 ? v.y : j == 6 ? v.z : v.w);
        s += focal_delta(l);
      }
    }
    sum += (cls >= 0) ? s : 0.0f;
  }
  for (int o = 32; o > 0; o >>= 1) sum += __shfl_down(sum, o, 64);
  int lane = threadIdx.x & 63, wid = threadIdx.x >> 6;
  if (lane == 0) sbuf[wid] = (double)sum;
  __syncthreads();
  if (threadIdx.x == 0) {
    atomicAdd(&acc[1], sbuf[0] + sbuf[1] + sbuf[2] + sbuf[3]);
  }
}

// ---------------- kernel 4: finalize ----------------

__global__ void final_kernel(const double* __restrict__ acc,
                             float* __restrict__ out) {
  if (threadIdx.x == 0) {
    double pn = acc[2] > 1.0 ? acc[2] : 1.0;
    out[0] = (float)(acc[0] / (pn * 4.0));
    out[1] = (float)(acc[1] / pn);
  }
}

// ---------------- launch ----------------

extern "C" void kernel_launch(void* const* d_in, const int* in_sizes, int n_in,
                              void* d_out, int out_size, void* d_ws, size_t ws_size,
                              hipStream_t stream) {
  const float* loc_data  = (const float*)d_in[0];
  const float* conf_data = (const float*)d_in[1];
  const float* priors    = (const float*)d_in[2];
  const float* targets   = (const float*)d_in[3];
  float* out = (float*)d_out;

  int P  = in_sizes[2] / 4;        // 16384
  int BP = in_sizes[0] / 4;        // B*P
  int B  = BP / P;                 // 32
  int O  = in_sizes[3] / (B * 5);  // 16

  // ws layout: bto (BP f32) | bti (BP i32) | rowcls (BP i32) | gkey | acc
  float* bto    = (float*)d_ws;
  int* bti      = (int*)((char*)d_ws + (size_t)BP * 4);
  int* rowcls   = (int*)((char*)d_ws + (size_t)BP * 8);
  unsigned long long* gkey =
      (unsigned long long*)((char*)d_ws + (size_t)BP * 12);
  double* acc   = (double*)((char*)d_ws + (size_t)BP * 12 + (size_t)B * O * 8);

  int nkey = B * O;
  hipLaunchKernelGGL(init_kernel, dim3(1), dim3(1024), 0, stream, acc, gkey, nkey);

  int nbx = (P + 255) / 256;
  hipLaunchKernelGGL(match_partial_kernel, dim3(nbx, B), dim3(256), 0, stream,
                     priors, targets, bto, bti, gkey, P, O);
  hipLaunchKernelGGL(match_override_kernel, dim3(B), dim3(64), 0, stream,
                     gkey, bto, bti, P, O);
  hipLaunchKernelGGL(loc_rowcls_kernel, dim3(512), dim3(256), 0, stream,
                     loc_data, priors, targets, bto, bti, rowcls, acc, B, P, O);
  hipLaunchKernelGGL(conf_loss_kernel, dim3(2048), dim3(256), 0, stream,
                     (const float4*)conf_data, rowcls, acc, BP * 10);
  hipLaunchKernelGGL(final_kernel, dim3(1), dim3(64), 0, stream, acc, out);
}